// Round 3
// baseline (36.235 us; speedup 1.0000x reference)
//
#include <hip/hip_runtime.h>
#include <float.h>
#include <math.h>

// Problem constants (from reference)
constexpr int B  = 16;
constexpr int VS = 10475;
constexpr int VO = 8192;
constexpr int K  = 64;
constexpr int PS = 1024;
constexpr int PO = 2048;

// Fast-path geometry
constexpr int P1_BLOCK = 128;
constexpr int Q        = PS / P1_BLOCK;   // 8 queries per thread
constexpr int JC_BIG   = 16;              // object-axis chunks per k (primary)
constexpr int JC_SMALL = 8;               // fallback if ws is smaller
constexpr int P2_BLOCK = 256;
constexpr int P2_GRID  = (K * PS) / P2_BLOCK;  // 256 blocks

// ---------------- pass 1: partial min d^2 per (jc, k, i) ----------------

template<int JC>
__global__ __launch_bounds__(P1_BLOCK)
void cl_pass1(const float* __restrict__ smplx_v,
              const float* __restrict__ object_v,
              const int*   __restrict__ smpl_part_idx,
              const int*   __restrict__ obj_part_idx,
              const int*   __restrict__ batch_idx,
              float*       __restrict__ partial)   // [JC][K][PS]
{
    constexpr int JCHUNK = PO / JC;
    __shared__ float4 so[JCHUNK];   // (ox,oy,oz, 0.5*|o|^2)

    const int blk = blockIdx.x;
    const int k   = blk / JC;
    const int jc  = blk % JC;
    const int tid = threadIdx.x;

    const int b = batch_idx[k];
    const float* __restrict__ ov = object_v + (size_t)b * VO * 3;

    // Gather this block's object chunk into LDS.
    #pragma unroll
    for (int jj = 0; jj < JCHUNK / P1_BLOCK; ++jj) {
        const int j  = jj * P1_BLOCK + tid;
        const int oj = obj_part_idx[k * PO + jc * JCHUNK + j];
        const float ox = ov[oj * 3 + 0];
        const float oy = ov[oj * 3 + 1];
        const float oz = ov[oj * 3 + 2];
        so[j] = make_float4(ox, oy, oz, 0.5f * (ox * ox + oy * oy + oz * oz));
    }

    // Load Q query points into registers (overlaps other waves' gather).
    float nsx[Q], nsy[Q], nsz[Q], s2[Q], mint[Q];
    #pragma unroll
    for (int q = 0; q < Q; ++q) {
        const int i  = tid + q * P1_BLOCK;
        const int si = smpl_part_idx[k * PS + i];
        const float* __restrict__ sv = smplx_v + ((size_t)b * VS + si) * 3;
        const float sx = sv[0], sy = sv[1], sz = sv[2];
        nsx[q] = -sx; nsy[q] = -sy; nsz[q] = -sz;
        s2[q]  = sx * sx + sy * sy + sz * sz;
        mint[q] = FLT_MAX;
    }
    __syncthreads();

    // min over chunk of (0.5*|o|^2 - s.o); each LDS broadcast feeds 32 VALU.
    #pragma unroll 4
    for (int j = 0; j < JCHUNK; ++j) {
        const float4 o = so[j];
        #pragma unroll
        for (int q = 0; q < Q; ++q) {
            float t = fmaf(o.x, nsx[q], o.w);
            t = fmaf(o.y, nsy[q], t);
            t = fmaf(o.z, nsz[q], t);
            mint[q] = fminf(mint[q], t);
        }
    }

    // d^2 = s2 + 2*min_t, clamped; coalesced store.
    float* __restrict__ dst = partial + (size_t)jc * (K * PS) + (size_t)k * PS;
    #pragma unroll
    for (int q = 0; q < Q; ++q) {
        dst[tid + q * P1_BLOCK] = fmaxf(fmaf(2.0f, mint[q], s2[q]), 0.0f);
    }
}

// ------- pass 2 (fused final): min over jc, sqrt, sum; last block finishes -------

template<int JC>
__global__ __launch_bounds__(P2_BLOCK)
void cl_pass2(const float* __restrict__ partial,  // [JC][K][PS]
              float*       __restrict__ p2,       // [P2_GRID]
              unsigned int* __restrict__ cnt,     // [1], zeroed before launch
              float*       __restrict__ out)
{
    __shared__ float red[P2_BLOCK];
    __shared__ bool  amLast;

    const int blk = blockIdx.x;
    const int tid = threadIdx.x;
    const int k   = blk >> 2;                 // 4 blocks per k
    const int i   = (blk & 3) * P2_BLOCK + tid;

    float m = partial[(size_t)k * PS + i];
    #pragma unroll
    for (int jc = 1; jc < JC; ++jc)
        m = fminf(m, partial[(size_t)jc * (K * PS) + (size_t)k * PS + i]);
    const float v = sqrtf(m);

    red[tid] = v;
    __syncthreads();
    for (int s = P2_BLOCK / 2; s > 0; s >>= 1) {
        if (tid < s) red[tid] += red[tid + s];
        __syncthreads();
    }
    if (tid == 0) {
        p2[blk] = red[0];
        __threadfence();
        const unsigned int old = atomicAdd(cnt, 1u);
        amLast = (old == (unsigned int)(P2_GRID - 1));
    }
    __syncthreads();

    if (amLast) {
        __threadfence();
        red[tid] = p2[tid];                   // P2_GRID == P2_BLOCK
        __syncthreads();
        for (int s = P2_BLOCK / 2; s > 0; s >>= 1) {
            if (tid < s) red[tid] += red[tid + s];
            __syncthreads();
        }
        if (tid == 0) out[0] = red[0] * (1.0f / (float)(K * PS));
    }
}

// ---------------- fallback path (tiny ws) ----------------

constexpr int FB_BLOCKS_PER_K = 4;
constexpr int FB_NBLOCKS = K * FB_BLOCKS_PER_K;

__global__ __launch_bounds__(256)
void cl_fallback_main(const float* __restrict__ smplx_v,
                      const float* __restrict__ object_v,
                      const int*   __restrict__ smpl_part_idx,
                      const int*   __restrict__ obj_part_idx,
                      const int*   __restrict__ batch_idx,
                      float*       __restrict__ partial)
{
    __shared__ float4 so[PO];
    __shared__ float  red[256];

    const int blk    = blockIdx.x;
    const int k      = blk / FB_BLOCKS_PER_K;
    const int ichunk = blk % FB_BLOCKS_PER_K;
    const int tid    = threadIdx.x;

    const int b = batch_idx[k];
    const float* __restrict__ ov = object_v + (size_t)b * VO * 3;

    for (int j = tid; j < PO; j += 256) {
        const int oj = obj_part_idx[k * PO + j];
        const float ox = ov[oj * 3 + 0];
        const float oy = ov[oj * 3 + 1];
        const float oz = ov[oj * 3 + 2];
        so[j] = make_float4(ox, oy, oz, 0.5f * (ox * ox + oy * oy + oz * oz));
    }
    __syncthreads();

    const int i  = ichunk * 256 + tid;
    const int si = smpl_part_idx[k * PS + i];
    const float* __restrict__ sv = smplx_v + ((size_t)b * VS + si) * 3;
    const float sx = sv[0], sy = sv[1], sz = sv[2];
    const float nsx = -sx, nsy = -sy, nsz = -sz;
    const float s2 = sx * sx + sy * sy + sz * sz;

    float mint = FLT_MAX;
    #pragma unroll 8
    for (int j = 0; j < PO; ++j) {
        const float4 o = so[j];
        float t = fmaf(o.x, nsx, o.w);
        t = fmaf(o.y, nsy, t);
        t = fmaf(o.z, nsz, t);
        mint = fminf(mint, t);
    }
    const float v = sqrtf(fmaxf(s2 + 2.0f * mint, 0.0f));

    red[tid] = v;
    __syncthreads();
    for (int s = 128; s > 0; s >>= 1) {
        if (tid < s) red[tid] += red[tid + s];
        __syncthreads();
    }
    if (tid == 0) partial[blk] = red[0];
}

__global__ __launch_bounds__(256)
void cl_fallback_final(const float* __restrict__ partial,
                       float*       __restrict__ out)
{
    __shared__ float red[256];
    const int tid = threadIdx.x;
    red[tid] = (tid < FB_NBLOCKS) ? partial[tid] : 0.0f;
    __syncthreads();
    for (int s = 128; s > 0; s >>= 1) {
        if (tid < s) red[tid] += red[tid + s];
        __syncthreads();
    }
    if (tid == 0) out[0] = red[0] * (1.0f / (float)(K * PS));
}

// ---------------- launcher ----------------

extern "C" void kernel_launch(void* const* d_in, const int* in_sizes, int n_in,
                              void* d_out, int out_size, void* d_ws, size_t ws_size,
                              hipStream_t stream)
{
    const float* smplx_v       = (const float*)d_in[0];
    const float* object_v      = (const float*)d_in[1];
    const int*   smpl_part_idx = (const int*)d_in[2];
    const int*   obj_part_idx  = (const int*)d_in[3];
    const int*   batch_idx     = (const int*)d_in[4];
    float*       out           = (float*)d_out;

    const size_t need16 = (size_t)(JC_BIG   * K * PS + P2_GRID + 16) * sizeof(float);
    const size_t need8  = (size_t)(JC_SMALL * K * PS + P2_GRID + 16) * sizeof(float);

    if (ws_size >= need16) {
        float*        partial = (float*)d_ws;                       // [16][K][PS]
        float*        p2      = partial + (size_t)JC_BIG * K * PS;  // [256]
        unsigned int* cnt     = (unsigned int*)(p2 + P2_GRID);      // [1]
        hipMemsetAsync(cnt, 0, sizeof(unsigned int), stream);
        cl_pass1<JC_BIG><<<K * JC_BIG, P1_BLOCK, 0, stream>>>(
            smplx_v, object_v, smpl_part_idx, obj_part_idx, batch_idx, partial);
        cl_pass2<JC_BIG><<<P2_GRID, P2_BLOCK, 0, stream>>>(partial, p2, cnt, out);
    } else if (ws_size >= need8) {
        float*        partial = (float*)d_ws;                        // [8][K][PS]
        float*        p2      = partial + (size_t)JC_SMALL * K * PS; // [256]
        unsigned int* cnt     = (unsigned int*)(p2 + P2_GRID);       // [1]
        hipMemsetAsync(cnt, 0, sizeof(unsigned int), stream);
        cl_pass1<JC_SMALL><<<K * JC_SMALL, P1_BLOCK, 0, stream>>>(
            smplx_v, object_v, smpl_part_idx, obj_part_idx, batch_idx, partial);
        cl_pass2<JC_SMALL><<<P2_GRID, P2_BLOCK, 0, stream>>>(partial, p2, cnt, out);
    } else {
        float* partial = (float*)d_ws;   // [FB_NBLOCKS]
        cl_fallback_main<<<FB_NBLOCKS, 256, 0, stream>>>(
            smplx_v, object_v, smpl_part_idx, obj_part_idx, batch_idx, partial);
        cl_fallback_final<<<1, 256, 0, stream>>>(partial, out);
    }
}

// Round 4
// 29.658 us; speedup vs baseline: 1.2218x; 1.2218x over previous
//
#include <hip/hip_runtime.h>
#include <float.h>
#include <math.h>

// Problem constants (from reference)
constexpr int B  = 16;
constexpr int VS = 10475;
constexpr int VO = 8192;
constexpr int K  = 64;
constexpr int PS = 1024;
constexpr int PO = 2048;

// Fast-path geometry
constexpr int JC       = 16;              // object-axis chunks per k
constexpr int JCHUNK   = PO / JC;         // 128
constexpr int P1_BLOCK = 128;
constexpr int Q        = PS / P1_BLOCK;   // 8 queries per thread
constexpr int P1_GRID  = K * JC;          // 1024 blocks = 4 per CU
constexpr int P2_BLOCK = 256;
constexpr int P2_GRID  = (K * PS) / P2_BLOCK;  // 256
constexpr int PREP_GRID = (K * PS) / 256;      // 256

// ---------------- prep: gather queries once, coalesced output ----------------

__global__ __launch_bounds__(256)
void cl_gather_q(const float* __restrict__ smplx_v,
                 const int*   __restrict__ smpl_part_idx,
                 const int*   __restrict__ batch_idx,
                 float4*      __restrict__ qg)      // [K][PS]: (sx,sy,sz,|s|^2)
{
    const int gid = blockIdx.x * 256 + threadIdx.x;   // over K*PS
    const int k   = gid / PS;
    const int b   = batch_idx[k];
    const int si  = smpl_part_idx[gid];
    const float* __restrict__ sv = smplx_v + ((size_t)b * VS + si) * 3;
    const float sx = sv[0], sy = sv[1], sz = sv[2];
    qg[gid] = make_float4(sx, sy, sz, sx * sx + sy * sy + sz * sz);
}

// ---------------- pass 1: partial min d^2 per (jc, k, i) ----------------

__global__ __launch_bounds__(P1_BLOCK)
void cl_pass1(const float* __restrict__ object_v,
              const int*   __restrict__ obj_part_idx,
              const int*   __restrict__ batch_idx,
              const float4* __restrict__ qg,       // [K][PS]
              float*       __restrict__ partial)   // [JC][K][PS]
{
    __shared__ float4 so[JCHUNK];   // (ox,oy,oz, 0.5*|o|^2) -> 2 KiB

    const int blk = blockIdx.x;
    const int k   = blk / JC;
    const int jc  = blk % JC;
    const int tid = threadIdx.x;

    const int b = batch_idx[k];
    const float* __restrict__ ov = object_v + (size_t)b * VO * 3;

    // Gather this block's object chunk into LDS (JCHUNK == P1_BLOCK: 1/thread).
    {
        const int oj = obj_part_idx[k * PO + jc * JCHUNK + tid];
        const float ox = ov[oj * 3 + 0];
        const float oy = ov[oj * 3 + 1];
        const float oz = ov[oj * 3 + 2];
        so[tid] = make_float4(ox, oy, oz, 0.5f * (ox * ox + oy * oy + oz * oz));
    }

    // Coalesced float4 query loads (pre-gathered).
    float sx[Q], sy[Q], sz[Q], s2[Q], mint[Q];
    const float4* __restrict__ q4 = qg + (size_t)k * PS;
    #pragma unroll
    for (int q = 0; q < Q; ++q) {
        const float4 s = q4[tid + q * P1_BLOCK];
        sx[q] = s.x; sy[q] = s.y; sz[q] = s.z; s2[q] = s.w;
        mint[q] = FLT_MAX;
    }
    __syncthreads();

    // min over chunk of (0.5*|o|^2 - s.o); pairs -> v_min3_f32.
    #pragma unroll 4
    for (int j = 0; j < JCHUNK; j += 2) {
        const float4 o0 = so[j];
        const float4 o1 = so[j + 1];
        #pragma unroll
        for (int q = 0; q < Q; ++q) {
            const float t0 = fmaf(o0.z, -sz[q], fmaf(o0.y, -sy[q], fmaf(o0.x, -sx[q], o0.w)));
            const float t1 = fmaf(o1.z, -sz[q], fmaf(o1.y, -sy[q], fmaf(o1.x, -sx[q], o1.w)));
            mint[q] = fminf(mint[q], fminf(t0, t1));
        }
    }

    // d^2 = s2 + 2*min_t, clamped; coalesced store.
    float* __restrict__ dst = partial + ((size_t)jc * K + k) * PS;
    #pragma unroll
    for (int q = 0; q < Q; ++q) {
        dst[tid + q * P1_BLOCK] = fmaxf(fmaf(2.0f, mint[q], s2[q]), 0.0f);
    }
}

// ---------------- pass 2: min over jc, sqrt, per-block sum ----------------

__global__ __launch_bounds__(P2_BLOCK)
void cl_pass2(const float* __restrict__ partial,  // [JC][K][PS]
              float*       __restrict__ part2)    // [P2_GRID]
{
    __shared__ float red[P2_BLOCK];
    const int blk = blockIdx.x;
    const int tid = threadIdx.x;
    const int k   = blk >> 2;                   // 4 blocks per k
    const int i   = (blk & 3) * P2_BLOCK + tid;

    const float* __restrict__ p = partial + (size_t)k * PS + i;
    float m = p[0];
    #pragma unroll
    for (int jc = 1; jc < JC; ++jc)
        m = fminf(m, p[(size_t)jc * (K * PS)]);
    const float v = sqrtf(m);

    red[tid] = v;
    __syncthreads();
    for (int s = P2_BLOCK / 2; s > 0; s >>= 1) {
        if (tid < s) red[tid] += red[tid + s];
        __syncthreads();
    }
    if (tid == 0) part2[blk] = red[0];
}

// ---------------- pass 3: final sum ----------------

__global__ __launch_bounds__(P2_GRID)
void cl_pass3(const float* __restrict__ part2, float* __restrict__ out)
{
    __shared__ float red[P2_GRID];
    const int tid = threadIdx.x;
    red[tid] = part2[tid];
    __syncthreads();
    for (int s = P2_GRID / 2; s > 0; s >>= 1) {
        if (tid < s) red[tid] += red[tid + s];
        __syncthreads();
    }
    if (tid == 0) out[0] = red[0] * (1.0f / (float)(K * PS));
}

// ---------------- fallback path (tiny ws) ----------------

constexpr int FB_BLOCKS_PER_K = 4;
constexpr int FB_NBLOCKS = K * FB_BLOCKS_PER_K;

__global__ __launch_bounds__(256)
void cl_fallback_main(const float* __restrict__ smplx_v,
                      const float* __restrict__ object_v,
                      const int*   __restrict__ smpl_part_idx,
                      const int*   __restrict__ obj_part_idx,
                      const int*   __restrict__ batch_idx,
                      float*       __restrict__ partial)
{
    __shared__ float4 so[PO];
    __shared__ float  red[256];

    const int blk    = blockIdx.x;
    const int k      = blk / FB_BLOCKS_PER_K;
    const int ichunk = blk % FB_BLOCKS_PER_K;
    const int tid    = threadIdx.x;

    const int b = batch_idx[k];
    const float* __restrict__ ov = object_v + (size_t)b * VO * 3;

    for (int j = tid; j < PO; j += 256) {
        const int oj = obj_part_idx[k * PO + j];
        const float ox = ov[oj * 3 + 0];
        const float oy = ov[oj * 3 + 1];
        const float oz = ov[oj * 3 + 2];
        so[j] = make_float4(ox, oy, oz, 0.5f * (ox * ox + oy * oy + oz * oz));
    }
    __syncthreads();

    const int i  = ichunk * 256 + tid;
    const int si = smpl_part_idx[k * PS + i];
    const float* __restrict__ sv = smplx_v + ((size_t)b * VS + si) * 3;
    const float sx = sv[0], sy = sv[1], sz = sv[2];
    const float s2 = sx * sx + sy * sy + sz * sz;

    float mint = FLT_MAX;
    #pragma unroll 8
    for (int j = 0; j < PO; ++j) {
        const float4 o = so[j];
        float t = fmaf(o.z, -sz, fmaf(o.y, -sy, fmaf(o.x, -sx, o.w)));
        mint = fminf(mint, t);
    }
    const float v = sqrtf(fmaxf(fmaf(2.0f, mint, s2), 0.0f));

    red[tid] = v;
    __syncthreads();
    for (int s = 128; s > 0; s >>= 1) {
        if (tid < s) red[tid] += red[tid + s];
        __syncthreads();
    }
    if (tid == 0) partial[blk] = red[0];
}

__global__ __launch_bounds__(256)
void cl_fallback_final(const float* __restrict__ partial,
                       float*       __restrict__ out)
{
    __shared__ float red[256];
    const int tid = threadIdx.x;
    red[tid] = (tid < FB_NBLOCKS) ? partial[tid] : 0.0f;
    __syncthreads();
    for (int s = 128; s > 0; s >>= 1) {
        if (tid < s) red[tid] += red[tid + s];
        __syncthreads();
    }
    if (tid == 0) out[0] = red[0] * (1.0f / (float)(K * PS));
}

// ---------------- launcher ----------------

extern "C" void kernel_launch(void* const* d_in, const int* in_sizes, int n_in,
                              void* d_out, int out_size, void* d_ws, size_t ws_size,
                              hipStream_t stream)
{
    const float* smplx_v       = (const float*)d_in[0];
    const float* object_v      = (const float*)d_in[1];
    const int*   smpl_part_idx = (const int*)d_in[2];
    const int*   obj_part_idx  = (const int*)d_in[3];
    const int*   batch_idx     = (const int*)d_in[4];
    float*       out           = (float*)d_out;

    // ws layout: qg [K*PS float4] | partial [JC*K*PS float] | part2 [P2_GRID float]
    const size_t qg_elems      = (size_t)K * PS;                 // float4
    const size_t partial_elems = (size_t)JC * K * PS;            // float
    const size_t need = qg_elems * sizeof(float4)
                      + (partial_elems + P2_GRID) * sizeof(float);

    if (ws_size >= need) {
        float4* qg      = (float4*)d_ws;
        float*  partial = (float*)(qg + qg_elems);
        float*  part2   = partial + partial_elems;

        cl_gather_q<<<PREP_GRID, 256, 0, stream>>>(
            smplx_v, smpl_part_idx, batch_idx, qg);
        cl_pass1<<<P1_GRID, P1_BLOCK, 0, stream>>>(
            object_v, obj_part_idx, batch_idx, qg, partial);
        cl_pass2<<<P2_GRID, P2_BLOCK, 0, stream>>>(partial, part2);
        cl_pass3<<<1, P2_GRID, 0, stream>>>(part2, out);
    } else {
        float* partial = (float*)d_ws;   // [FB_NBLOCKS]
        cl_fallback_main<<<FB_NBLOCKS, 256, 0, stream>>>(
            smplx_v, object_v, smpl_part_idx, obj_part_idx, batch_idx, partial);
        cl_fallback_final<<<1, 256, 0, stream>>>(partial, out);
    }
}